// Round 5
// baseline (107.803 us; speedup 1.0000x reference)
//
#include <hip/hip_runtime.h>
#include <hip/hip_cooperative_groups.h>
#include <math.h>

namespace cg = cooperative_groups;

#define NB 32
#define NH 168
#define ND 512
#define NHIST 336
#define NFORE 168
#define NL 504
#define NF 8
#define GRID 512   // 2 blocks/CU x 256 CUs -> cooperative co-residency guaranteed

__device__ inline float waveSum(float v) {
    #pragma unroll
    for (int m = 1; m < 64; m <<= 1) v += __shfl_xor(v, m, 64);
    return v;
}
__device__ inline float waveMax(float v) {
    #pragma unroll
    for (int m = 1; m < 64; m <<= 1) v = fmaxf(v, __shfl_xor(v, m, 64));
    return v;
}
__device__ inline float waveMin(float v) {
    #pragma unroll
    for (int m = 1; m < 64; m <<= 1) v = fminf(v, __shfl_xor(v, m, 64));
    return v;
}
__device__ inline float grpSum32(float v) {
    v += __shfl_xor(v, 1, 64);
    v += __shfl_xor(v, 2, 64);
    v += __shfl_xor(v, 4, 64);
    v += __shfl_xor(v, 8, 64);
    v += __shfl_xor(v, 16, 64);
    return v;
}

__global__ __launch_bounds__(256, 2) void k_all(
        const float* __restrict__ y, const float* __restrict__ wh,
        const float* __restrict__ wf,
        const float* __restrict__ Wq, const float* __restrict__ bq,
        const float* __restrict__ Wk, const float* __restrict__ Wv,
        const float* __restrict__ bv, const float* __restrict__ Ws,
        const float* __restrict__ bs,
        float* __restrict__ uk, float* __restrict__ wvs,
        float* __restrict__ bvs, float* __restrict__ ckp,
        float* __restrict__ logits, float* __restrict__ out) {
    cg::grid_group grid = cg::this_grid();
    const int blk = blockIdx.x, tid = threadIdx.x;
    const int lane = tid & 63, w = tid >> 6;
    __shared__ __align__(16) float xT[NF][NL];   // 16128 B; reused as reduce buf in ph2
    __shared__ float xmx[NF], xmn[NF];
    __shared__ float red[256];

    const int b1 = blk >> 4, hb = blk & 15;      // 32 b x 16 h-blocks

    // ---------------- phase 0: stage weather + pre-work ----------------
    for (int i = tid; i < NL * NF; i += 256) {
        const int l = i >> 3, f = i & 7;
        const float v = (l < NHIST) ? wh[(b1 * NHIST + l) * NF + f]
                                    : wf[(b1 * NFORE + (l - NHIST)) * NF + f];
        xT[f][l] = v;
    }

    if (blk < 16) {
        // uk[col] = sum_e Wk[e]*Wq[e,col], 32 cols for this block
        const int col = tid & 31, rg = tid >> 5;        // rg: 0..7
        const int colbase = blk << 5;
        float acc = 0.f;
        #pragma unroll
        for (int r = 0; r < 64; ++r) {
            const int e = rg + 8 * r;
            acc += Wk[e] * Wq[e * ND + colbase + col];
        }
        red[rg * 32 + col] = acc;
    } else if (blk < 80) {
        // wvs[e]/bvs[e], 8 rows per block
        const int g = tid >> 5, sl = tid & 31;
        const int e = ((blk - 16) << 3) + g;
        const float4* __restrict__ wsr = (const float4*)(Ws + (size_t)e * ND);
        const float4* __restrict__ wv4 = (const float4*)Wv;
        const float4* __restrict__ bv4 = (const float4*)bv;
        float a1 = 0.f, a2 = 0.f;
        #pragma unroll
        for (int i = 0; i < 4; ++i) {
            const int q = sl + 32 * i;
            const float4 x = wsr[q];
            const float4 v = wv4[q];
            const float4 c = bv4[q];
            a1 += x.x * v.x + x.y * v.y + x.z * v.z + x.w * v.w;
            a2 += x.x * c.x + x.y * c.y + x.z * c.z + x.w * c.w;
        }
        a1 = grpSum32(a1);
        a2 = grpSum32(a2);
        if (sl == 0) { wvs[e] = a1; bvs[e] = 8.f * a2 + bs[e]; }
    } else if (blk == 80) {
        float p = bq[tid] * Wk[tid] + bq[tid + 256] * Wk[tid + 256];
        p = waveSum(p);
        if (lane == 0) red[w] = p;
    }
    __syncthreads();
    if (blk < 16 && tid < 32) {
        float s = 0.f;
        #pragma unroll
        for (int i = 0; i < 8; ++i) s += red[i * 32 + tid];
        uk[(blk << 5) + tid] = s;
    }
    if (blk == 80 && tid == 0) *ckp = red[0] + red[1] + red[2] + red[3];

    // per-f min/max of staged weather
    for (int f = w; f < NF; f += 4) {
        float mx = -1e30f, mn = 1e30f;
        #pragma unroll
        for (int j = 0; j < 8; ++j) {
            const int idx = lane + 64 * j;
            if (idx < NL) {
                const float v = xT[f][idx];
                mx = fmaxf(mx, v); mn = fminf(mn, v);
            }
        }
        mx = waveMax(mx); mn = waveMin(mn);
        if (lane == 0) { xmx[f] = mx; xmn[f] = mn; }
    }

    grid.sync();

    // ------- phase 1: logits; 32 lanes/h; each slot: h = hb + 16*(slot+8r) -------
    {
        const int slot = tid >> 5, sl = tid & 31;
        const float scale = 22.627416997969522f;      // sqrt(512)
        const float4* __restrict__ uk4 = (const float4*)uk;
        const float4* __restrict__ wv4 = (const float4*)wvs;
        const float4* __restrict__ bv4 = (const float4*)bvs;
        const float ck = *ckp;
        #pragma unroll
        for (int r = 0; r < 2; ++r) {
            const int h = hb + 16 * (slot + 8 * r);   // 0..255, guarded
            if (h < NH) {
                const float4* __restrict__ yr =
                    (const float4*)(y + ((size_t)b1 * NH + h) * ND);
                float d1 = 0.f, d2 = 0.f, d3 = 0.f;
                #pragma unroll
                for (int i = 0; i < 4; ++i) {
                    const int q = sl + 32 * i;        // 512B-contig per 32-lane group
                    const float4 yv = yr[q];
                    const float4 u = uk4[q];
                    const float4 v = wv4[q];
                    const float4 c = bv4[q];
                    d1 += yv.x * u.x + yv.y * u.y + yv.z * u.z + yv.w * u.w;
                    d2 += yv.x * v.x + yv.y * v.y + yv.z * v.z + yv.w * v.w;
                    d3 += yv.x * c.x + yv.y * c.y + yv.z * c.z + yv.w * c.w;
                }
                d1 = grpSum32(d1); d2 = grpSum32(d2); d3 = grpSum32(d3);
                const float a = (d1 + ck) / scale;

                float S = 0.f;
                #pragma unroll
                for (int f = 0; f < NF; ++f) {
                    const float m = (a >= 0.f) ? a * xmx[f] : a * xmn[f];
                    const float4* __restrict__ xp = (const float4*)&xT[f][0];
                    float num = 0.f, den = 0.f;
                    #pragma unroll
                    for (int i = 0; i < 4; ++i) {
                        const int q = sl + 32 * i;
                        if (q < 126) {                // 504 = 126*4
                            const float4 x = xp[q];
                            float e0 = __expf(fmaf(a, x.x, -m));
                            float e1 = __expf(fmaf(a, x.y, -m));
                            float e2 = __expf(fmaf(a, x.z, -m));
                            float e3 = __expf(fmaf(a, x.w, -m));
                            den += (e0 + e1) + (e2 + e3);
                            num += x.x * e0 + x.y * e1 + x.z * e2 + x.w * e3;
                        }
                    }
                    num = grpSum32(num); den = grpSum32(den);
                    S += num / den;
                }
                if (sl == 0) logits[b1 * NH + h] = (S * d2 + d3) / scale;
            }
        }
    }

    grid.sync();

    // ---------------- phase 2: softmax over H + weighted sum + add ----------------
    {
        const int b = blk >> 4, dc = blk & 15;        // 16 chunks of 8 float4 (128B)
        float* lg = red;                              // [168] logits -> P
        if (tid < NH) lg[tid] = logits[b * NH + tid];
        __syncthreads();
        if (w == 0) {
            float mx = -1e30f;
            for (int i = lane; i < NH; i += 64) mx = fmaxf(mx, lg[i]);
            mx = waveMax(mx);
            float z = 0.f;
            for (int i = lane; i < NH; i += 64) z += __expf(lg[i] - mx);
            z = waveSum(z);
            if (lane == 0) { red[200] = mx; red[201] = 1.f / z; }
        }
        __syncthreads();
        const float mx = red[200], invz = red[201];
        if (tid < NH) lg[tid] = __expf(lg[tid] - mx) * invz;
        __syncthreads();

        const int c = tid & 7, hw = tid >> 3;         // 8 float4 cols, 32 h-groups
        const float4* __restrict__ y4 = (const float4*)y;
        const size_t base = ((size_t)b * NH) * 128 + dc * 8 + c;
        float4 yv[6];
        float4 acc = make_float4(0.f, 0.f, 0.f, 0.f);
        #pragma unroll
        for (int k = 0; k < 6; ++k) {
            const int h = hw + 32 * k;
            if (h < NH) {
                yv[k] = y4[base + (size_t)h * 128];
                const float P = lg[h];
                acc.x += P * yv[k].x; acc.y += P * yv[k].y;
                acc.z += P * yv[k].z; acc.w += P * yv[k].w;
            }
        }
        float4* fl4 = (float4*)&xT[0][0];             // reuse LDS (264 float4 needed)
        fl4[hw * 8 + c] = acc;
        __syncthreads();
        if (tid < 8) {
            float4 s = fl4[tid];
            for (int i = 1; i < 32; ++i) {
                const float4 t = fl4[i * 8 + tid];
                s.x += t.x; s.y += t.y; s.z += t.z; s.w += t.w;
            }
            fl4[256 + tid] = s;
        }
        __syncthreads();
        const float4 fin = fl4[256 + c];
        float4* __restrict__ out4 = (float4*)out;
        #pragma unroll
        for (int k = 0; k < 6; ++k) {
            const int h = hw + 32 * k;
            if (h < NH) {
                float4 o = yv[k];
                o.x += fin.x; o.y += fin.y; o.z += fin.z; o.w += fin.w;
                out4[base + (size_t)h * 128] = o;
            }
        }
    }
}

extern "C" void kernel_launch(void* const* d_in, const int* in_sizes, int n_in,
                              void* d_out, int out_size, void* d_ws, size_t ws_size,
                              hipStream_t stream) {
    const void* y  = d_in[0];
    const void* wh = d_in[1];
    const void* wf = d_in[2];
    const void* Wq = d_in[3];
    const void* bq = d_in[4];
    const void* Wk = d_in[5];
    // d_in[6] = bk: cancels in the softmax over L — unused.
    const void* Wv = d_in[7];
    const void* bv = d_in[8];
    const void* Ws = d_in[9];
    const void* bs = d_in[10];
    void* out = d_out;
    float* ws = (float*)d_ws;

    void* uk     = (void*)(ws);            // 512
    void* wvs    = (void*)(ws + 512);      // 512
    void* bvs    = (void*)(ws + 1024);     // 512
    void* ckp    = (void*)(ws + 1536);     // 1
    void* logits = (void*)(ws + 1600);     // B*H = 5376

    void* args[] = { (void*)&y, (void*)&wh, (void*)&wf, (void*)&Wq, (void*)&bq,
                     (void*)&Wk, (void*)&Wv, (void*)&bv, (void*)&Ws, (void*)&bs,
                     (void*)&uk, (void*)&wvs, (void*)&bvs, (void*)&ckp,
                     (void*)&logits, (void*)&out };
    hipLaunchCooperativeKernel((void*)k_all, dim3(GRID), dim3(256), args, 0, stream);
}

// Round 7
// 26.638 us; speedup vs baseline: 4.0470x; 4.0470x over previous
//
#include <hip/hip_runtime.h>
#include <math.h>

#define NB 32
#define NH 168
#define ND 512
#define NHIST 336
#define NFORE 168
#define NL 504
#define NF 8
#define LOG2E 1.4426950408889634f

__device__ inline float waveSum(float v) {
    #pragma unroll
    for (int m = 1; m < 64; m <<= 1) v += __shfl_xor(v, m, 64);
    return v;
}
__device__ inline float waveMax(float v) {
    #pragma unroll
    for (int m = 1; m < 64; m <<= 1) v = fmaxf(v, __shfl_xor(v, m, 64));
    return v;
}
__device__ inline float grpSum32(float v) {
    v += __shfl_xor(v, 1, 64);
    v += __shfl_xor(v, 2, 64);
    v += __shfl_xor(v, 4, 64);
    v += __shfl_xor(v, 8, 64);
    v += __shfl_xor(v, 16, 64);
    return v;
}
__device__ inline float grpMax32(float v) {
    v = fmaxf(v, __shfl_xor(v, 1, 64));
    v = fmaxf(v, __shfl_xor(v, 2, 64));
    v = fmaxf(v, __shfl_xor(v, 4, 64));
    v = fmaxf(v, __shfl_xor(v, 8, 64));
    v = fmaxf(v, __shfl_xor(v, 16, 64));
    return v;
}
__device__ inline float grpMin32(float v) {
    v = fminf(v, __shfl_xor(v, 1, 64));
    v = fminf(v, __shfl_xor(v, 2, 64));
    v = fminf(v, __shfl_xor(v, 4, 64));
    v = fminf(v, __shfl_xor(v, 8, 64));
    v = fminf(v, __shfl_xor(v, 16, 64));
    return v;
}

// K1 (113 blocks x 256):
//  blk 0..15 : uk[col] = sum_e Wk[e]*Wq[e,col]   (32 cols/block)
//  blk 16..79: wvs[e]=Ws[e,:]·Wv; bvs[e]=8*(Ws[e,:]·bv)+bs[e]  (8 rows/block)
//  blk 80    : ck = bq·Wk
//  blk 81+b  : transpose weather[b] -> xTg[b][f][l] and per-(b,f) min/max
__global__ __launch_bounds__(256) void k_pre(
        const float* __restrict__ wh, const float* __restrict__ wf,
        const float* __restrict__ Wq, const float* __restrict__ bq,
        const float* __restrict__ Wk, const float* __restrict__ Wv,
        const float* __restrict__ bv, const float* __restrict__ Ws,
        const float* __restrict__ bs,
        float* __restrict__ uk, float* __restrict__ wvs,
        float* __restrict__ bvs, float* __restrict__ ckp,
        float* __restrict__ xTg, float* __restrict__ xmxg,
        float* __restrict__ xmng) {
    const int blk = blockIdx.x, tid = threadIdx.x;
    const int lane = tid & 63, w = tid >> 6;
    __shared__ float red[256];
    if (blk < 16) {
        const int col = tid & 31, rg = tid >> 5;       // rg 0..7
        const int colbase = blk << 5;
        float a0 = 0.f, a1 = 0.f, a2 = 0.f, a3 = 0.f;
        #pragma unroll
        for (int r = 0; r < 16; ++r) {
            const int e = rg + 32 * r;                 // 4 interleaved chains
            a0 += Wk[e]      * Wq[e * ND + colbase + col];
            a1 += Wk[e + 8]  * Wq[(e + 8) * ND + colbase + col];
            a2 += Wk[e + 16] * Wq[(e + 16) * ND + colbase + col];
            a3 += Wk[e + 24] * Wq[(e + 24) * ND + colbase + col];
        }
        red[tid] = (a0 + a1) + (a2 + a3);
        __syncthreads();
        if (tid < 32) {
            float s = 0.f;
            #pragma unroll
            for (int i = 0; i < 8; ++i) s += red[i * 32 + tid];
            uk[colbase + tid] = s;
        }
    } else if (blk < 80) {
        const int g = tid >> 5, sl = tid & 31;
        const int e = ((blk - 16) << 3) + g;
        const float4* __restrict__ wsr = (const float4*)(Ws + (size_t)e * ND);
        const float4* __restrict__ wv4 = (const float4*)Wv;
        const float4* __restrict__ bv4 = (const float4*)bv;
        float a1 = 0.f, a2 = 0.f;
        #pragma unroll
        for (int i = 0; i < 4; ++i) {
            const int q = sl + 32 * i;
            const float4 x = wsr[q];
            const float4 v = wv4[q];
            const float4 c = bv4[q];
            a1 += x.x * v.x + x.y * v.y + x.z * v.z + x.w * v.w;
            a2 += x.x * c.x + x.y * c.y + x.z * c.z + x.w * c.w;
        }
        a1 = grpSum32(a1);
        a2 = grpSum32(a2);
        if (sl == 0) { wvs[e] = a1; bvs[e] = 8.f * a2 + bs[e]; }
    } else if (blk == 80) {
        float p = bq[tid] * Wk[tid] + bq[tid + 256] * Wk[tid + 256];
        p = waveSum(p);
        if (lane == 0) red[w] = p;
        __syncthreads();
        if (tid == 0) *ckp = red[0] + red[1] + red[2] + red[3];
    } else {
        const int b = blk - 81;
        // transpose [l][f] -> xTg[(b*8+f)*504 + l]
        const float4* __restrict__ wh4 = (const float4*)wh;
        const float4* __restrict__ wf4 = (const float4*)wf;
        #pragma unroll
        for (int t = 0; t < 4; ++t) {
            const int j = tid + 256 * t;               // 1008 float4 total
            if (j < NL * 2) {
                const int l = j >> 1, f0 = (j & 1) * 4;
                const float4 v = (l < NHIST)
                    ? wh4[(b * NHIST + l) * 2 + (j & 1)]
                    : wf4[(b * NFORE + (l - NHIST)) * 2 + (j & 1)];
                xTg[(size_t)(b * NF + f0 + 0) * NL + l] = v.x;
                xTg[(size_t)(b * NF + f0 + 1) * NL + l] = v.y;
                xTg[(size_t)(b * NF + f0 + 2) * NL + l] = v.z;
                xTg[(size_t)(b * NF + f0 + 3) * NL + l] = v.w;
            }
        }
        __syncthreads();
        // per-(b,f) min/max readback (L1/L2-hot)
        const int f = tid >> 5, sl = tid & 31;
        const float4* __restrict__ xb = (const float4*)xTg + (size_t)(b * NF + f) * (NL / 4);
        float mx = -1e30f, mn = 1e30f;
        #pragma unroll
        for (int i = 0; i < 4; ++i) {
            const int q = sl + 32 * i;
            if (q < NL / 4) {
                const float4 x = xb[q];
                mx = fmaxf(fmaxf(mx, x.x), fmaxf(x.y, fmaxf(x.z, x.w)));
                mn = fminf(fminf(mn, x.x), fminf(x.y, fminf(x.z, x.w)));
            }
        }
        mx = grpMax32(mx); mn = grpMin32(mn);
        if (sl == 0) { xmxg[b * NF + f] = mx; xmng[b * NF + f] = mn; }
    }
}

// K2 (672 blocks x 256): no LDS, no syncthreads. 32 lanes/h, 8 h/block.
__global__ __launch_bounds__(256) void k_main(
        const float* __restrict__ y, const float* __restrict__ xTg,
        const float* __restrict__ xmxg, const float* __restrict__ xmng,
        const float* __restrict__ uk, const float* __restrict__ wvs,
        const float* __restrict__ bvs, const float* __restrict__ ckp,
        float* __restrict__ logits) {
    const int blk = blockIdx.x, tid = threadIdx.x;
    const int b = blk / 21, hb = blk % 21;
    const int slot = tid >> 5, sl = tid & 31;
    const int h = hb * 8 + slot;                       // 0..167 exact
    const float scale = 22.627416997969522f;           // sqrt(512)

    const float4* __restrict__ yr  = (const float4*)(y + ((size_t)b * NH + h) * ND);
    const float4* __restrict__ uk4 = (const float4*)uk;
    const float4* __restrict__ wv4 = (const float4*)wvs;
    const float4* __restrict__ bv4 = (const float4*)bvs;
    float d1 = 0.f, d2 = 0.f, d3 = 0.f;
    #pragma unroll
    for (int i = 0; i < 4; ++i) {
        const int q = sl + 32 * i;                     // 512B-contig per 32-lane group
        const float4 yv = yr[q];
        const float4 u = uk4[q];
        const float4 v = wv4[q];
        const float4 c = bv4[q];
        d1 += yv.x * u.x + yv.y * u.y + yv.z * u.z + yv.w * u.w;
        d2 += yv.x * v.x + yv.y * v.y + yv.z * v.z + yv.w * v.w;
        d3 += yv.x * c.x + yv.y * c.y + yv.z * c.z + yv.w * c.w;
    }
    d1 = grpSum32(d1); d2 = grpSum32(d2); d3 = grpSum32(d3);
    const float a = (d1 + *ckp) / scale;
    const float a2 = a * LOG2E;                        // fold log2e into the exponent

    float xmv[NF], xnv[NF];
    #pragma unroll
    for (int f = 0; f < NF; ++f) {
        xmv[f] = xmxg[b * NF + f];
        xnv[f] = xmng[b * NF + f];
    }

    float numf[NF], denf[NF];
    const float4* __restrict__ xb = (const float4*)xTg + (size_t)(b * NF) * (NL / 4);
    #pragma unroll
    for (int f = 0; f < NF; ++f) {
        const float m2 = a2 * ((a >= 0.f) ? xmv[f] : xnv[f]);
        float num = 0.f, den = 0.f;
        #pragma unroll
        for (int i = 0; i < 4; ++i) {
            const int q = sl + 32 * i;
            if (q < NL / 4) {                          // 126 float4
                const float4 x = xb[f * (NL / 4) + q];
                const float e0 = __builtin_amdgcn_exp2f(fmaf(a2, x.x, -m2));
                const float e1 = __builtin_amdgcn_exp2f(fmaf(a2, x.y, -m2));
                const float e2 = __builtin_amdgcn_exp2f(fmaf(a2, x.z, -m2));
                const float e3 = __builtin_amdgcn_exp2f(fmaf(a2, x.w, -m2));
                den += (e0 + e1) + (e2 + e3);
                num += x.x * e0 + x.y * e1;
                num += x.z * e2 + x.w * e3;
            }
        }
        numf[f] = num; denf[f] = den;
    }
    // 16 interleaved butterflies (pipelined, not 8 serial chains)
    #pragma unroll
    for (int m = 1; m < 32; m <<= 1) {
        #pragma unroll
        for (int f = 0; f < NF; ++f) {
            numf[f] += __shfl_xor(numf[f], m, 64);
            denf[f] += __shfl_xor(denf[f], m, 64);
        }
    }
    float S = 0.f;
    #pragma unroll
    for (int f = 0; f < NF; ++f)
        S += numf[f] * __builtin_amdgcn_rcpf(denf[f]);
    if (sl == 0) logits[b * NH + h] = (S * d2 + d3) / scale;
}

// K3 (512 blocks x 256): (b, dc) with dc = 8-float4 (128B) chunk; softmax over H
// + P-weighted sum + broadcast add; y kept in regs.
__global__ __launch_bounds__(256) void k_final(
        const float* __restrict__ y, const float* __restrict__ logits,
        float* __restrict__ out) {
    const int b = blockIdx.x >> 4, dc = blockIdx.x & 15;
    const int tid = threadIdx.x, lane = tid & 63, w = tid >> 6;
    __shared__ float lg[NH];
    __shared__ float mzv[2];
    __shared__ float4 fl4[32];
    __shared__ float4 ffin[8];
    if (tid < NH) lg[tid] = logits[b * NH + tid];
    __syncthreads();
    if (w == 0) {
        float mx = -1e30f;
        for (int i = lane; i < NH; i += 64) mx = fmaxf(mx, lg[i]);
        mx = waveMax(mx);
        float z = 0.f;
        for (int i = lane; i < NH; i += 64) z += __expf(lg[i] - mx);
        z = waveSum(z);
        if (lane == 0) { mzv[0] = mx; mzv[1] = 1.f / z; }
    }
    __syncthreads();
    const float mx = mzv[0], invz = mzv[1];
    if (tid < NH) lg[tid] = __expf(lg[tid] - mx) * invz;  // lg := P
    __syncthreads();

    const int c = tid & 7, hw = tid >> 3;              // 8 float4 cols, 32 h-groups
    const float4* __restrict__ y4 = (const float4*)y;
    const size_t base = ((size_t)b * NH) * 128 + dc * 8 + c;
    float4 yv[6];
    float4 acc = make_float4(0.f, 0.f, 0.f, 0.f);
    #pragma unroll
    for (int k = 0; k < 6; ++k) {
        const int hh = hw + 32 * k;
        if (hh < NH) {
            yv[k] = y4[base + (size_t)hh * 128];
            const float P = lg[hh];
            acc.x += P * yv[k].x; acc.y += P * yv[k].y;
            acc.z += P * yv[k].z; acc.w += P * yv[k].w;
        }
    }
    // butterfly over the 8 h-groups within each wave (lane bits 3,4,5)
    #pragma unroll
    for (int m = 8; m < 64; m <<= 1) {
        acc.x += __shfl_xor(acc.x, m, 64);
        acc.y += __shfl_xor(acc.y, m, 64);
        acc.z += __shfl_xor(acc.z, m, 64);
        acc.w += __shfl_xor(acc.w, m, 64);
    }
    if (lane < 8) fl4[w * 8 + lane] = acc;
    __syncthreads();
    if (tid < 8) {
        float4 s = fl4[tid];
        #pragma unroll
        for (int i = 1; i < 4; ++i) {
            const float4 t = fl4[i * 8 + tid];
            s.x += t.x; s.y += t.y; s.z += t.z; s.w += t.w;
        }
        ffin[tid] = s;
    }
    __syncthreads();
    const float4 fin = ffin[c];
    float4* __restrict__ out4 = (float4*)out;
    #pragma unroll
    for (int k = 0; k < 6; ++k) {
        const int hh = hw + 32 * k;
        if (hh < NH) {
            float4 o = yv[k];
            o.x += fin.x; o.y += fin.y; o.z += fin.z; o.w += fin.w;
            out4[base + (size_t)hh * 128] = o;
        }
    }
}

extern "C" void kernel_launch(void* const* d_in, const int* in_sizes, int n_in,
                              void* d_out, int out_size, void* d_ws, size_t ws_size,
                              hipStream_t stream) {
    const float* y  = (const float*)d_in[0];
    const float* wh = (const float*)d_in[1];
    const float* wf = (const float*)d_in[2];
    const float* Wq = (const float*)d_in[3];
    const float* bq = (const float*)d_in[4];
    const float* Wk = (const float*)d_in[5];
    // d_in[6] = bk: cancels in the softmax over L — unused.
    const float* Wv = (const float*)d_in[7];
    const float* bv = (const float*)d_in[8];
    const float* Ws = (const float*)d_in[9];
    const float* bs = (const float*)d_in[10];
    float* out = (float*)d_out;
    float* ws = (float*)d_ws;

    float* uk     = ws;             // 512
    float* wvs    = ws + 512;       // 512
    float* bvs    = ws + 1024;      // 512
    float* ckp    = ws + 1536;      // 1
    float* logits = ws + 1600;      // 5376
    float* xTg    = ws + 8192;      // 32*8*504 = 129024 (16B-aligned)
    float* xmxg   = ws + 8192 + 129024;   // 256
    float* xmng   = ws + 8192 + 129280;   // 256

    k_pre<<<113, 256, 0, stream>>>(wh, wf, Wq, bq, Wk, Wv, bv, Ws, bs,
                                   uk, wvs, bvs, ckp, xTg, xmxg, xmng);
    k_main<<<NB * 21, 256, 0, stream>>>(y, xTg, xmxg, xmng, uk, wvs, bvs, ckp, logits);
    k_final<<<NB * 16, 256, 0, stream>>>(y, logits, out);
}